// Round 6
// baseline (9953.053 us; speedup 1.0000x reference)
//
#include <hip/hip_runtime.h>
#include <stdint.h>

#define BATCH 128
#define TSTEPS 250
#define NIN 700
#define NHID 1024
#define NBR 4
#define NOUT 20
#define KDIM 1724          // NIN + NHID
#define NR 4096            // NHID * NBR
#define VTH 0.5f

// ---------------- setup kernels ----------------

__global__ void setup_small(const float* __restrict__ tau_m1, const float* __restrict__ tau_n,
                            const float* __restrict__ tau_m2, const float* __restrict__ W2,
                            float* __restrict__ alpha1, float* __restrict__ beta,
                            float* __restrict__ alpha2, float* __restrict__ W2T) {
    int i = blockIdx.x * blockDim.x + threadIdx.x;
    if (i < NHID)  alpha1[i] = 1.f / (1.f + expf(-tau_m1[i]));
    if (i < NR)    beta[i]   = 1.f / (1.f + expf(-tau_n[i]));   // tau_n row-major [HID][BR] == flat r
    if (i < 32)    alpha2[i] = (i < NOUT) ? 1.f / (1.f + expf(-tau_m2[i])) : 0.f;
    if (i < NHID * 32) {                                        // W2T padded [1024][32]
        int j = i >> 5, o = i & 31;
        W2T[i] = (o < NOUT) ? W2[o * NHID + j] : 0.f;
    }
}

// W1xT[k][r] (k<700) and W1hTb[blk][n][16] masked transposes
__global__ void setup_weights(const float* __restrict__ W1, const int* __restrict__ mask,
                              float* __restrict__ W1xT, float* __restrict__ W1hTb) {
    const int total1 = NIN * NR;            // 2,867,200
    const int total2 = 256 * 16384;         // 4,194,304
    for (int i = blockIdx.x * blockDim.x + threadIdx.x; i < total1 + total2;
         i += gridDim.x * blockDim.x) {
        if (i < total1) {
            int k = i >> 12, r = i & 4095;
            size_t src = (size_t)r * KDIM + k;
            W1xT[i] = W1[src] * (float)mask[src];
        } else {
            int j = i - total1;
            int blk = j >> 14, rem = j & 16383;
            int n = rem >> 4, rl = rem & 15;
            int r = (blk << 4) + rl;
            size_t src = (size_t)r * KDIM + NIN + n;
            W1hTb[j] = W1[src] * (float)mask[src];
        }
    }
}

__global__ void init_state(const float* __restrict__ mem1_0, const float* __restrict__ mem2_0,
                           float* __restrict__ mem1, float* __restrict__ mem2,
                           float* __restrict__ spk2, float* __restrict__ d_inp,
                           uint32_t* __restrict__ spkdat, uint32_t* __restrict__ spkseq) {
    int i = blockIdx.x * blockDim.x + threadIdx.x;
    if (i < BATCH * NR) d_inp[i] = 0.f;
    if (i < BATCH * NHID) mem1[i] = mem1_0[i];
    if (i < BATCH * NOUT) { mem2[i] = mem2_0[i]; spk2[i] = 0.f; }
    if (i < 4096) spkdat[i] = 0u;                       // slot 0 = initial zero spikes
    if (i < (TSTEPS + 1) * 256) spkseq[i] = (i < 256) ? 1u : 0u;   // slot-0 flags pre-set
}

// ---------------- FFX GEMM: ffx[dt][b][r] = sum_k x[b][t0+dt][k]*W1xT[k][r] + b1[r] ----------------

#define GBM 128
#define GBN 128
#define GBK 16

__global__ __launch_bounds__(256) void ffx_gemm(const float* __restrict__ x,
                                                const float* __restrict__ W1xT,
                                                const float* __restrict__ b1,
                                                float* __restrict__ ffx, int t0) {
    __shared__ float As[GBK][GBM];
    __shared__ float Bs[GBK][GBN];
    int dt = blockIdx.x, bn = blockIdx.y;
    int tid = threadIdx.x;
    int tn = tid & 15, tm = tid >> 4;

    float acc[8][8];
#pragma unroll
    for (int i = 0; i < 8; ++i)
#pragma unroll
        for (int j = 0; j < 8; ++j) acc[i][j] = 0.f;

    int m_l = tid >> 1;
    const float* xrow = x + ((size_t)m_l * TSTEPS + t0 + dt) * NIN;
    int kh = (tid & 1) * 8;
    int kb = tid >> 4;
    int nb = (tid & 15) * 8;

    for (int k0 = 0; k0 < NIN; k0 += GBK) {
        float av[8];
#pragma unroll
        for (int u = 0; u < 8; ++u) {
            int k = k0 + kh + u;
            av[u] = (k < NIN) ? xrow[k] : 0.f;
        }
#pragma unroll
        for (int u = 0; u < 8; ++u) As[kh + u][m_l] = av[u];

        bool kok = (k0 + kb) < NIN;
        const float* bp = W1xT + (size_t)(k0 + kb) * NR + bn * GBN + nb;
        float bv[8];
#pragma unroll
        for (int u = 0; u < 8; ++u) bv[u] = kok ? bp[u] : 0.f;
#pragma unroll
        for (int u = 0; u < 8; ++u) Bs[kb][nb + u] = bv[u];

        __syncthreads();
#pragma unroll
        for (int kk = 0; kk < GBK; ++kk) {
            float a[8], b[8];
#pragma unroll
            for (int u = 0; u < 8; ++u) a[u] = As[kk][tm * 8 + u];
#pragma unroll
            for (int u = 0; u < 8; ++u) b[u] = Bs[kk][tn * 8 + u];
#pragma unroll
            for (int i = 0; i < 8; ++i)
#pragma unroll
                for (int j = 0; j < 8; ++j) acc[i][j] += a[i] * b[j];
        }
        __syncthreads();
    }

    float bias[8];
#pragma unroll
    for (int j = 0; j < 8; ++j) bias[j] = b1[bn * GBN + tn * 8 + j];
#pragma unroll
    for (int i = 0; i < 8; ++i) {
        int brow = tm * 8 + i;
        float* cp = ffx + ((size_t)dt * BATCH + brow) * NR + bn * GBN + tn * 8;
#pragma unroll
        for (int j = 0; j < 8; ++j) cp[j] = acc[i][j] + bias[j];
    }
}

// ---------------- persistent time-loop kernel (dataflow sync, no global barrier) ----------------
// 256 blocks x 1024 threads; ~103 KB LDS forces 1 block/CU -> all 256 co-resident.
// Block blk owns r-tile [blk*16, blk*16+16) = neurons [blk*4, blk*4+4).
// Spike slots are WRITE-ONCE: spkdat[t+1][blk][g] (g=0..15), published via per-block flag
// spkseq[t+1][blk] (release). Consumers spin on 256 distinct flags -> no atomic contention,
// no lockstep: blocks may skew, stragglers amortize.
// Spike dword g: nibble j = 4 spike bits (neurons 4blk..4blk+3) of batch 8g+j.
// Per-batch masks: 32 dwords, bit p of word w = spike of neuron 32w+p.

__global__ __launch_bounds__(1024) void persist3(
    const float* __restrict__ alpha1, const float* __restrict__ beta,
    const float* __restrict__ alpha2, float* __restrict__ mem1,
    float* __restrict__ mem2, float* __restrict__ spk2,
    float* __restrict__ d_inp, const float* __restrict__ W1hTb,
    const float* __restrict__ W2T, const float* __restrict__ ffx,
    const float* __restrict__ b2v, float* __restrict__ out,
    uint32_t* __restrict__ spkdat, uint32_t* __restrict__ spkseq,
    int t0, int tc, int last) {
    __shared__ float lds_W[NHID * 17];       // 69,632 B (padded, conflict-free column reads)
    __shared__ uint32_t lds_spk[4096];       // 16,384 B (raw spike words; reused as f32 scratch)
    __shared__ uint32_t lds_mask[128 * 33];  // 16,896 B (per-batch 32-word masks, padded)

    const int blk = blockIdx.x;
    const int tid = threadIdx.x;

    // ---- stage recurrent weight slice ONCE for the whole chunk
    {
        const float4* wsrc = (const float4*)(W1hTb + (size_t)blk * 16384);
        for (int i4 = tid; i4 < 4096; i4 += 1024) {
            float4 v = wsrc[i4];
            int n = i4 >> 2, rb = (i4 & 3) * 4;
            lds_W[n * 17 + rb + 0] = v.x;
            lds_W[n * 17 + rb + 1] = v.y;
            lds_W[n * 17 + rb + 2] = v.z;
            lds_W[n * 17 + rb + 3] = v.w;
        }
    }

    const int r_l = tid & 15;
    const int bg  = tid >> 4;                // 0..63
    const int r_g = (blk << 4) + r_l;
    const int neuron = (blk << 2) + (r_l >> 2);
    const float beta_r = beta[r_g];
    const float al = alpha1[neuron];
    const int b0 = bg * 2, b1 = bg * 2 + 1;

    // register-resident layer-1 state
    float di0 = d_inp[(size_t)b0 * NR + r_g];
    float di1 = d_inp[(size_t)b1 * NR + r_g];
    float mm0 = mem1[b0 * NHID + neuron];
    float mm1 = mem1[b1 * NHID + neuron];

    // layer-2 ownership: blocks 0..31, 4 batches each, 8-way word-split per batch
    const int o2 = tid & 31;
    const int sub = tid >> 5;                // 0..31
    const bool l2red = (blk < 32) && ((sub & 7) == 0);
    const int b2b = (blk << 2) + (sub >> 3);
    float m2 = 0.f, s2v = 0.f, a2 = 0.f, bo = 0.f;
    if (l2red && o2 < NOUT) {
        a2 = alpha2[o2];
        bo = b2v[o2];
        m2 = mem2[b2b * NOUT + o2];
        s2v = spk2[b2b * NOUT + o2];
    }
    float* lds_f = (float*)lds_spk;          // phase-2 partial scratch (lds_spk is dead there)

    const int iters = tc + (last ? 1 : 0);
    for (int it = 0; it < iters; ++it) {
        const int tt = t0 + it;

        // ---- dataflow wait: all 256 producer flags for slot tt (256 distinct addresses)
        {
            const uint32_t* fl = spkseq + (size_t)tt * 256;
            if (tid < 256) {
                while (__hip_atomic_load(fl + tid, __ATOMIC_ACQUIRE,
                                         __HIP_MEMORY_SCOPE_AGENT) == 0u)
                    __builtin_amdgcn_s_sleep(1);
            }
            __syncthreads();   // all data ready; also orders prev-iter LDS reads vs stage writes
        }

        // ---- prefetch ffx for this step (private, plain loads)
        float ff0 = 0.f, ff1 = 0.f;
        if (tt < TSTEPS) {
            const float* fr = ffx + (size_t)it * ((size_t)BATCH * NR);
            ff0 = fr[(size_t)b0 * NR + r_g];
            ff1 = fr[(size_t)b1 * NR + r_g];
        }

        // ---- stage spike words of slot tt (agent-coherent loads; XOR bank-swizzled store)
        {
            const uint32_t* spg = spkdat + (size_t)tt * 4096;
#pragma unroll
            for (int k = 0; k < 4; ++k) {
                int idx = tid + (k << 10);
                lds_spk[idx ^ ((idx >> 7) & 31)] =
                    __hip_atomic_load(&spg[idx], __ATOMIC_RELAXED, __HIP_MEMORY_SCOPE_AGENT);
            }
        }
        __syncthreads();

        // ---- transpose to per-batch 32-word dense masks: bit p of word w = neuron 32w+p
        {
            const int w = tid & 31;          // mask word
            const int bq = tid >> 5;         // batch quad 0..31
            const int g = bq >> 1;           // source dword index (batch octet)
            uint32_t sw[8];
#pragma unroll
            for (int m = 0; m < 8; ++m) {
                int raw = (w << 7) + (m << 4) + g;   // block (8w+m), word16 g
                sw[m] = lds_spk[raw ^ (w & 31)];
            }
#pragma unroll
            for (int u = 0; u < 4; ++u) {
                const int b = (bq << 2) + u;
                const int j = ((bq & 1) << 2) + u;   // b & 7
                uint32_t word = 0;
#pragma unroll
                for (int m = 0; m < 8; ++m)
                    word |= ((sw[m] >> (j << 2)) & 0xFu) << (m << 2);
                lds_mask[b * 33 + w] = word;
            }
        }
        __syncthreads();

        // ---------- phase 1: recurrent accumulate + dendrite + mem1 + spike ----------
        if (tt < TSTEPS) {
            uint32_t* spn = spkdat + (size_t)(tt + 1) * 4096;
            const uint32_t* mw0 = &lds_mask[b0 * 33];
            const uint32_t* mw1 = &lds_mask[b1 * 33];
            float acc0 = 0.f, acc1 = 0.f;
            for (int w = 0; w < 32; ++w) {
                uint32_t bits0 = mw0[w];
                while (bits0) {
                    int p = __builtin_ctz(bits0);
                    bits0 &= bits0 - 1;
                    acc0 += lds_W[((w << 5) + p) * 17 + r_l];
                }
                uint32_t bits1 = mw1[w];
                while (bits1) {
                    int p = __builtin_ctz(bits1);
                    bits1 &= bits1 - 1;
                    acc1 += lds_W[((w << 5) + p) * 17 + r_l];
                }
            }
            di0 = beta_r * di0 + (1.f - beta_r) * (acc0 + ff0);
            di1 = beta_r * di1 + (1.f - beta_r) * (acc1 + ff1);
            float ls0 = di0 + __shfl_xor(di0, 1); ls0 += __shfl_xor(ls0, 2);
            float ls1 = di1 + __shfl_xor(di1, 1); ls1 += __shfl_xor(ls1, 2);
            float sp0 = (float)((mw0[neuron >> 5] >> (neuron & 31)) & 1u);
            float sp1 = (float)((mw1[neuron >> 5] >> (neuron & 31)) & 1u);
            float mn0 = mm0 * al + (1.f - al) * ls0 - VTH * sp0;  mm0 = mn0;
            float mn1 = mm1 * al + (1.f - al) * ls1 - VTH * sp1;  mm1 = mn1;
            bool sk0 = (mn0 - VTH) > 0.f;
            bool sk1 = (mn1 - VTH) > 0.f;
            unsigned long long bal0 = __ballot(sk0 && ((r_l & 3) == 0));
            unsigned long long bal1 = __ballot(sk1 && ((r_l & 3) == 0));
            uint32_t dw = 0;
#pragma unroll
            for (int q = 0; q < 4; ++q) {
                uint32_t nb0 = (uint32_t)((bal0 >> (q * 16)) & 1ull)
                             | ((uint32_t)((bal0 >> (q * 16 + 4)) & 1ull) << 1)
                             | ((uint32_t)((bal0 >> (q * 16 + 8)) & 1ull) << 2)
                             | ((uint32_t)((bal0 >> (q * 16 + 12)) & 1ull) << 3);
                uint32_t nb1 = (uint32_t)((bal1 >> (q * 16)) & 1ull)
                             | ((uint32_t)((bal1 >> (q * 16 + 4)) & 1ull) << 1)
                             | ((uint32_t)((bal1 >> (q * 16 + 8)) & 1ull) << 2)
                             | ((uint32_t)((bal1 >> (q * 16 + 12)) & 1ull) << 3);
                dw |= (nb0 << (q * 8)) | (nb1 << (q * 8 + 4));
            }
            if ((tid & 63) == 0)
                __hip_atomic_store(&spn[(blk << 4) + (tid >> 6)], dw, __ATOMIC_RELAXED,
                                   __HIP_MEMORY_SCOPE_AGENT);
        }

        // ---- publish this block's slot tt+1 (before phase 2, to unblock other blocks ASAP)
        __syncthreads();                      // drain all 16 data stores of this block
        if (tt < TSTEPS && tid == 0)
            __hip_atomic_store(&spkseq[(size_t)(tt + 1) * 256 + blk], 1u,
                               __ATOMIC_RELEASE, __HIP_MEMORY_SCOPE_AGENT);

        // ---------- phase 2 (for step tt-1): layer 2 + log_softmax, 8-way split ----------
        if (tt > 0 && blk < 32) {
            const int bp = (blk << 2) + (sub >> 3);
            const int q = sub & 7;
            const uint32_t* mw = &lds_mask[bp * 33];
            float part = 0.f;
#pragma unroll
            for (int w = q * 4; w < q * 4 + 4; ++w) {
                uint32_t bits = mw[w];
                while (bits) {
                    int p = __builtin_ctz(bits);
                    bits &= bits - 1;
                    part += W2T[(((w << 5) + p) << 5) + o2];
                }
            }
            lds_f[(sub << 5) + o2] = part;
        }
        if (blk < 32) __syncthreads();
        if (tt > 0 && l2red) {
            float d2 = bo;
#pragma unroll
            for (int j = 0; j < 8; ++j) d2 += lds_f[((sub + j) << 5) + o2];
            float m2n = m2 * a2 + (1.f - a2) * d2 - VTH * s2v;
            m2 = m2n;
            s2v = ((m2n - VTH) > 0.f) ? 1.f : 0.f;
            float v = (o2 < NOUT) ? m2n : -3.4e38f;
#pragma unroll
            for (int off = 16; off >= 1; off >>= 1) v = fmaxf(v, __shfl_xor(v, off, 32));
            float e = (o2 < NOUT) ? expf(m2n - v) : 0.f;
            float s = e;
#pragma unroll
            for (int off = 16; off >= 1; off >>= 1) s += __shfl_xor(s, off, 32);
            if (o2 < NOUT) out[((size_t)b2b * NOUT + o2) * TSTEPS + (tt - 1)] = (m2n - v) - logf(s);
        }
    }

    // ---- save state for next chunk
    d_inp[(size_t)b0 * NR + r_g] = di0;
    d_inp[(size_t)b1 * NR + r_g] = di1;
    if ((r_l & 3) == 0) {
        mem1[b0 * NHID + neuron] = mm0;
        mem1[b1 * NHID + neuron] = mm1;
    }
    if (l2red && o2 < NOUT) {
        mem2[b2b * NOUT + o2] = m2;
        spk2[b2b * NOUT + o2] = s2v;
    }
}

// ---------------- host ----------------

extern "C" void kernel_launch(void* const* d_in, const int* in_sizes, int n_in,
                              void* d_out, int out_size, void* d_ws, size_t ws_size,
                              hipStream_t stream) {
    const float* x      = (const float*)d_in[0];
    const float* W1     = (const float*)d_in[1];
    const float* b1     = (const float*)d_in[2];
    const float* tau_m1 = (const float*)d_in[3];
    const float* tau_n  = (const float*)d_in[4];
    const float* W2     = (const float*)d_in[5];
    const float* b2     = (const float*)d_in[6];
    const float* tau_m2 = (const float*)d_in[7];
    const float* mem1_0 = (const float*)d_in[8];
    const float* mem2_0 = (const float*)d_in[9];
    const int*   mask   = (const int*)d_in[10];
    float* out = (float*)d_out;

    float* ws = (float*)d_ws;
    size_t F = 0;
    float* alpha1 = ws + F; F += 1024;
    float* beta   = ws + F; F += 4096;
    float* alpha2 = ws + F; F += 32;
    float* mem1   = ws + F; F += BATCH * NHID;
    float* mem2   = ws + F; F += BATCH * NOUT;
    float* spk2   = ws + F; F += BATCH * NOUT;
    float* d_inp  = ws + F; F += BATCH * NR;
    float* W1xT   = ws + F; F += (size_t)NIN * NR;
    float* W1hTb  = ws + F; F += (size_t)256 * 16384;
    float* W2T    = ws + F; F += NHID * 32;
    uint32_t* spkdat = (uint32_t*)(ws + F); F += (size_t)(TSTEPS + 1) * 4096;  // write-once slots
    uint32_t* spkseq = (uint32_t*)(ws + F); F += (size_t)(TSTEPS + 1) * 256;   // publish flags
    float* ffx = ws + F;

    size_t ws_f = ws_size / 4;
    size_t avail = (ws_f > F) ? (ws_f - F) : 0;
    size_t per_t = (size_t)BATCH * NR;          // 524288 floats per timestep
    int Tc = (int)(avail / per_t);
    if (Tc < 1) Tc = 1;
    if (Tc > TSTEPS) Tc = TSTEPS;

    hipLaunchKernelGGL(setup_small, dim3(128), dim3(256), 0, stream,
                       tau_m1, tau_n, tau_m2, W2, alpha1, beta, alpha2, W2T);
    hipLaunchKernelGGL(setup_weights, dim3(2048), dim3(256), 0, stream, W1, mask, W1xT, W1hTb);
    hipLaunchKernelGGL(init_state, dim3(2048), dim3(256), 0, stream,
                       mem1_0, mem2_0, mem1, mem2, spk2, d_inp, spkdat, spkseq);

    int chunk_start = 0;
    while (chunk_start < TSTEPS) {
        int tc = TSTEPS - chunk_start;
        if (tc > Tc) tc = Tc;
        int last = (chunk_start + tc >= TSTEPS) ? 1 : 0;

        hipLaunchKernelGGL(ffx_gemm, dim3(tc, 32), dim3(256), 0, stream,
                           x, W1xT, b1, ffx, chunk_start);
        hipLaunchKernelGGL(persist3, dim3(256), dim3(1024), 0, stream,
                           alpha1, beta, alpha2, mem1, mem2, spk2, d_inp, W1hTb, W2T,
                           ffx, b2, out, spkdat, spkseq, chunk_start, tc, last);

        chunk_start += tc;
    }
}

// Round 7
// 7414.787 us; speedup vs baseline: 1.3423x; 1.3423x over previous
//
#include <hip/hip_runtime.h>
#include <stdint.h>

#define BATCH 128
#define TSTEPS 250
#define NIN 700
#define NHID 1024
#define NBR 4
#define NOUT 20
#define KDIM 1724          // NIN + NHID
#define NR 4096            // NHID * NBR
#define VTH 0.5f

// ---------------- setup kernels ----------------

__global__ void setup_small(const float* __restrict__ tau_m1, const float* __restrict__ tau_n,
                            const float* __restrict__ tau_m2, const float* __restrict__ W2,
                            float* __restrict__ alpha1, float* __restrict__ beta,
                            float* __restrict__ alpha2, float* __restrict__ W2T) {
    int i = blockIdx.x * blockDim.x + threadIdx.x;
    if (i < NHID)  alpha1[i] = 1.f / (1.f + expf(-tau_m1[i]));
    if (i < NR)    beta[i]   = 1.f / (1.f + expf(-tau_n[i]));   // tau_n row-major [HID][BR] == flat r
    if (i < 32)    alpha2[i] = (i < NOUT) ? 1.f / (1.f + expf(-tau_m2[i])) : 0.f;
    if (i < NHID * 32) {                                        // W2T padded [1024][32]
        int j = i >> 5, o = i & 31;
        W2T[i] = (o < NOUT) ? W2[o * NHID + j] : 0.f;
    }
}

// W1xT[k][r] (k<700) and W1hTb[blk][n][16] masked transposes
__global__ void setup_weights(const float* __restrict__ W1, const int* __restrict__ mask,
                              float* __restrict__ W1xT, float* __restrict__ W1hTb) {
    const int total1 = NIN * NR;            // 2,867,200
    const int total2 = 256 * 16384;         // 4,194,304
    for (int i = blockIdx.x * blockDim.x + threadIdx.x; i < total1 + total2;
         i += gridDim.x * blockDim.x) {
        if (i < total1) {
            int k = i >> 12, r = i & 4095;
            size_t src = (size_t)r * KDIM + k;
            W1xT[i] = W1[src] * (float)mask[src];
        } else {
            int j = i - total1;
            int blk = j >> 14, rem = j & 16383;
            int n = rem >> 4, rl = rem & 15;
            int r = (blk << 4) + rl;
            size_t src = (size_t)r * KDIM + NIN + n;
            W1hTb[j] = W1[src] * (float)mask[src];
        }
    }
}

__global__ void init_state(const float* __restrict__ mem1_0, const float* __restrict__ mem2_0,
                           float* __restrict__ mem1, float* __restrict__ mem2,
                           float* __restrict__ spk2, float* __restrict__ d_inp,
                           uint32_t* __restrict__ spkg, uint32_t* __restrict__ bar) {
    int i = blockIdx.x * blockDim.x + threadIdx.x;
    if (i < BATCH * NR) d_inp[i] = 0.f;
    if (i < BATCH * NHID) mem1[i] = mem1_0[i];
    if (i < BATCH * NOUT) { mem2[i] = mem2_0[i]; spk2[i] = 0.f; }
    if (i < 8192) spkg[i] = 0u;   // both spike-word buffers (2 x 256 x 16 dwords)
    if (i < 1024) bar[i] = 0u;    // barrier tree — re-zeroed every launch/replay
}

// ---------------- FFX GEMM: ffx[dt][b][r] = sum_k x[b][t0+dt][k]*W1xT[k][r] + b1[r] ----------------

#define GBM 128
#define GBN 128
#define GBK 16

__global__ __launch_bounds__(256) void ffx_gemm(const float* __restrict__ x,
                                                const float* __restrict__ W1xT,
                                                const float* __restrict__ b1,
                                                float* __restrict__ ffx, int t0) {
    __shared__ float As[GBK][GBM];
    __shared__ float Bs[GBK][GBN];
    int dt = blockIdx.x, bn = blockIdx.y;
    int tid = threadIdx.x;
    int tn = tid & 15, tm = tid >> 4;

    float acc[8][8];
#pragma unroll
    for (int i = 0; i < 8; ++i)
#pragma unroll
        for (int j = 0; j < 8; ++j) acc[i][j] = 0.f;

    int m_l = tid >> 1;
    const float* xrow = x + ((size_t)m_l * TSTEPS + t0 + dt) * NIN;
    int kh = (tid & 1) * 8;
    int kb = tid >> 4;
    int nb = (tid & 15) * 8;

    for (int k0 = 0; k0 < NIN; k0 += GBK) {
        float av[8];
#pragma unroll
        for (int u = 0; u < 8; ++u) {
            int k = k0 + kh + u;
            av[u] = (k < NIN) ? xrow[k] : 0.f;
        }
#pragma unroll
        for (int u = 0; u < 8; ++u) As[kh + u][m_l] = av[u];

        bool kok = (k0 + kb) < NIN;
        const float* bp = W1xT + (size_t)(k0 + kb) * NR + bn * GBN + nb;
        float bv[8];
#pragma unroll
        for (int u = 0; u < 8; ++u) bv[u] = kok ? bp[u] : 0.f;
#pragma unroll
        for (int u = 0; u < 8; ++u) Bs[kb][nb + u] = bv[u];

        __syncthreads();
#pragma unroll
        for (int kk = 0; kk < GBK; ++kk) {
            float a[8], b[8];
#pragma unroll
            for (int u = 0; u < 8; ++u) a[u] = As[kk][tm * 8 + u];
#pragma unroll
            for (int u = 0; u < 8; ++u) b[u] = Bs[kk][tn * 8 + u];
#pragma unroll
            for (int i = 0; i < 8; ++i)
#pragma unroll
                for (int j = 0; j < 8; ++j) acc[i][j] += a[i] * b[j];
        }
        __syncthreads();
    }

    float bias[8];
#pragma unroll
    for (int j = 0; j < 8; ++j) bias[j] = b1[bn * GBN + tn * 8 + j];
#pragma unroll
    for (int i = 0; i < 8; ++i) {
        int brow = tm * 8 + i;
        float* cp = ffx + ((size_t)dt * BATCH + brow) * NR + bn * GBN + tn * 8;
#pragma unroll
        for (int j = 0; j < 8; ++j) cp[j] = acc[i][j] + bias[j];
    }
}

// ---------------- persistent time-loop kernel (two-level tree barrier) ----------------
// 256 blocks x 1024 threads; ~103 KB LDS forces 1 block/CU -> all 256 co-resident.
// Block blk owns r-tile [blk*16, blk*16+16) = neurons [blk*4, blk*4+4).
// Thread (bg=tid>>4, r_l=tid&15) owns batches {2bg, 2bg+1}.
// Barrier: 16 group counters (blk&15, cache-line spaced) + 1 root. Arrive = release-add
// group; group-last release-adds root (root += 16 per epoch). Wait = relaxed spin on root.
// Serialized same-line RMW chain: 256 (round 5) -> 32. Phase 2 runs AFTER arrive so its
// latency hides in other blocks' spin window.
// Spike words: spkg[parity][blk][g], g=0..15; nibble j of dword g = 4 spike bits
// (neurons 4blk..4blk+3) of batch 8g+j. Per-batch masks: 32 dwords, bit p of word w =
// spike of neuron 32w+p.

__global__ __launch_bounds__(1024) void persist4(
    const float* __restrict__ alpha1, const float* __restrict__ beta,
    const float* __restrict__ alpha2, float* __restrict__ mem1,
    float* __restrict__ mem2, float* __restrict__ spk2,
    float* __restrict__ d_inp, const float* __restrict__ W1hTb,
    const float* __restrict__ W2T, const float* __restrict__ ffx,
    const float* __restrict__ b2v, float* __restrict__ out,
    uint32_t* __restrict__ spkg, uint32_t* __restrict__ bar,
    int t0, int tc, int last, int epoch0) {
    __shared__ float lds_W[NHID * 17];       // 69,632 B (padded, conflict-free column reads)
    __shared__ uint32_t lds_spk[4096];       // 16,384 B (raw spike words, XOR-swizzled)
    __shared__ uint32_t lds_mask[128 * 33];  // 16,896 B (per-batch 32-word masks, padded)

    const int blk = blockIdx.x;
    const int tid = threadIdx.x;

    // ---- stage recurrent weight slice ONCE for the whole chunk
    {
        const float4* wsrc = (const float4*)(W1hTb + (size_t)blk * 16384);
        for (int i4 = tid; i4 < 4096; i4 += 1024) {
            float4 v = wsrc[i4];
            int n = i4 >> 2, rb = (i4 & 3) * 4;
            lds_W[n * 17 + rb + 0] = v.x;
            lds_W[n * 17 + rb + 1] = v.y;
            lds_W[n * 17 + rb + 2] = v.z;
            lds_W[n * 17 + rb + 3] = v.w;
        }
    }

    const int r_l = tid & 15;
    const int bg  = tid >> 4;                // 0..63
    const int r_g = (blk << 4) + r_l;
    const int neuron = (blk << 2) + (r_l >> 2);
    const float beta_r = beta[r_g];
    const float al = alpha1[neuron];
    const int b0 = bg * 2, b1 = bg * 2 + 1;

    // register-resident layer-1 state
    float di0 = d_inp[(size_t)b0 * NR + r_g];
    float di1 = d_inp[(size_t)b1 * NR + r_g];
    float mm0 = mem1[b0 * NHID + neuron];
    float mm1 = mem1[b1 * NHID + neuron];

    // layer-2 ownership: blocks 0..15, 8 batches each; active threads: (sub&3)==0
    const int o2 = tid & 31;
    const int sub = tid >> 5;                // 0..31
    const bool l2blk = (blk < 16) && ((sub & 3) == 0);
    const int b2b = (blk << 3) + (sub >> 2);
    float m2 = 0.f, s2v = 0.f, a2 = 0.f, bo = 0.f;
    if (l2blk && o2 < NOUT) {
        a2 = alpha2[o2];
        bo = b2v[o2];
        m2 = mem2[b2b * NOUT + o2];
        s2v = spk2[b2b * NOUT + o2];
    }

    uint32_t* grp = bar + 32 + ((blk & 15) << 5);   // this block's group counter line

    const int iters = tc + (last ? 1 : 0);
    for (int it = 0; it < iters; ++it) {
        const int tt = t0 + it;

        // ---- prefetch ffx for this step (independent of spikes; overlaps the spin)
        float ff0 = 0.f, ff1 = 0.f;
        if (tt < TSTEPS) {
            const float* fr = ffx + (size_t)it * ((size_t)BATCH * NR);
            ff0 = fr[(size_t)b0 * NR + r_g];
            ff1 = fr[(size_t)b1 * NR + r_g];
        }

        // ---- wait for barrier epoch (epoch0 + it); it==0 synced by kernel boundary
        if (it > 0) {
            if (tid == 0) {
                uint32_t tgt = 16u * (uint32_t)(epoch0 + it);
                while (__hip_atomic_load(&bar[0], __ATOMIC_RELAXED,
                                         __HIP_MEMORY_SCOPE_AGENT) < tgt)
                    __builtin_amdgcn_s_sleep(2);
            }
            __syncthreads();
        }

        // ---- stage spike words (agent-coherent loads; XOR bank-swizzled store)
        {
            const uint32_t* spg = spkg + (size_t)((tt + 1) & 1) * 4096;
#pragma unroll
            for (int k = 0; k < 4; ++k) {
                int idx = tid + (k << 10);
                lds_spk[idx ^ ((idx >> 7) & 31)] =
                    __hip_atomic_load(&spg[idx], __ATOMIC_RELAXED, __HIP_MEMORY_SCOPE_AGENT);
            }
        }
        __syncthreads();

        // ---- transpose to per-batch 32-word dense masks: bit p of word w = neuron 32w+p
        {
            const int w = tid & 31;          // mask word
            const int bq = tid >> 5;         // batch quad 0..31
            const int g = bq >> 1;           // source dword index (batch octet)
            uint32_t sw[8];
#pragma unroll
            for (int m = 0; m < 8; ++m) {
                int raw = (w << 7) + (m << 4) + g;   // block (8w+m), word16 g
                sw[m] = lds_spk[raw ^ (w & 31)];
            }
#pragma unroll
            for (int u = 0; u < 4; ++u) {
                const int b = (bq << 2) + u;
                const int j = ((bq & 1) << 2) + u;   // b & 7
                uint32_t word = 0;
#pragma unroll
                for (int m = 0; m < 8; ++m)
                    word |= ((sw[m] >> (j << 2)) & 0xFu) << (m << 2);
                lds_mask[b * 33 + w] = word;
            }
        }
        __syncthreads();

        // ---------- phase 1: recurrent accumulate + dendrite + mem1 + spike ----------
        if (tt < TSTEPS) {
            uint32_t* spn = spkg + (size_t)(tt & 1) * 4096;
            const uint32_t* mw0 = &lds_mask[b0 * 33];
            const uint32_t* mw1 = &lds_mask[b1 * 33];
            float acc0 = 0.f, acc1 = 0.f;
            for (int w = 0; w < 32; ++w) {
                uint32_t bits0 = mw0[w];
                while (bits0) {
                    int p = __builtin_ctz(bits0);
                    bits0 &= bits0 - 1;
                    acc0 += lds_W[((w << 5) + p) * 17 + r_l];
                }
                uint32_t bits1 = mw1[w];
                while (bits1) {
                    int p = __builtin_ctz(bits1);
                    bits1 &= bits1 - 1;
                    acc1 += lds_W[((w << 5) + p) * 17 + r_l];
                }
            }
            di0 = beta_r * di0 + (1.f - beta_r) * (acc0 + ff0);
            di1 = beta_r * di1 + (1.f - beta_r) * (acc1 + ff1);
            float ls0 = di0 + __shfl_xor(di0, 1); ls0 += __shfl_xor(ls0, 2);
            float ls1 = di1 + __shfl_xor(di1, 1); ls1 += __shfl_xor(ls1, 2);
            float sp0 = (float)((mw0[neuron >> 5] >> (neuron & 31)) & 1u);
            float sp1 = (float)((mw1[neuron >> 5] >> (neuron & 31)) & 1u);
            float mn0 = mm0 * al + (1.f - al) * ls0 - VTH * sp0;  mm0 = mn0;
            float mn1 = mm1 * al + (1.f - al) * ls1 - VTH * sp1;  mm1 = mn1;
            bool sk0 = (mn0 - VTH) > 0.f;
            bool sk1 = (mn1 - VTH) > 0.f;
            unsigned long long bal0 = __ballot(sk0 && ((r_l & 3) == 0));
            unsigned long long bal1 = __ballot(sk1 && ((r_l & 3) == 0));
            uint32_t dw = 0;
#pragma unroll
            for (int q = 0; q < 4; ++q) {
                uint32_t nb0 = (uint32_t)((bal0 >> (q * 16)) & 1ull)
                             | ((uint32_t)((bal0 >> (q * 16 + 4)) & 1ull) << 1)
                             | ((uint32_t)((bal0 >> (q * 16 + 8)) & 1ull) << 2)
                             | ((uint32_t)((bal0 >> (q * 16 + 12)) & 1ull) << 3);
                uint32_t nb1 = (uint32_t)((bal1 >> (q * 16)) & 1ull)
                             | ((uint32_t)((bal1 >> (q * 16 + 4)) & 1ull) << 1)
                             | ((uint32_t)((bal1 >> (q * 16 + 8)) & 1ull) << 2)
                             | ((uint32_t)((bal1 >> (q * 16 + 12)) & 1ull) << 3);
                dw |= (nb0 << (q * 8)) | (nb1 << (q * 8 + 4));
            }
            if ((tid & 63) == 0)
                __hip_atomic_store(&spn[(blk << 4) + (tid >> 6)], dw, __ATOMIC_RELAXED,
                                   __HIP_MEMORY_SCOPE_AGENT);
        }

        // ---- arrive (before phase 2: stores drained by the barrier's vmcnt(0))
        __syncthreads();
        if (it + 1 < iters && tid == 0) {
            uint32_t e16 = 16u * (uint32_t)(epoch0 + it + 1);
            uint32_t old = __hip_atomic_fetch_add(grp, 1u, __ATOMIC_RELEASE,
                                                  __HIP_MEMORY_SCOPE_AGENT);
            if (old == e16 - 1u)    // last of the 16-block group this epoch
                __hip_atomic_fetch_add(&bar[0], 1u, __ATOMIC_RELEASE,
                                       __HIP_MEMORY_SCOPE_AGENT);
        }

        // ---------- phase 2 (for step tt-1): layer 2 + log_softmax (hides in spin window) ----------
        if (tt > 0 && l2blk) {
            const uint32_t* mw = &lds_mask[b2b * 33];
            float d2 = bo;
            for (int w = 0; w < 32; ++w) {
                uint32_t bits = mw[w];
                while (bits) {
                    int p = __builtin_ctz(bits);
                    bits &= bits - 1;
                    d2 += W2T[(((w << 5) + p) << 5) + o2];
                }
            }
            float m2n = m2 * a2 + (1.f - a2) * d2 - VTH * s2v;
            m2 = m2n;
            s2v = ((m2n - VTH) > 0.f) ? 1.f : 0.f;
            float v = (o2 < NOUT) ? m2n : -3.4e38f;
#pragma unroll
            for (int off = 16; off >= 1; off >>= 1) v = fmaxf(v, __shfl_xor(v, off, 32));
            float e = (o2 < NOUT) ? expf(m2n - v) : 0.f;
            float s = e;
#pragma unroll
            for (int off = 16; off >= 1; off >>= 1) s += __shfl_xor(s, off, 32);
            if (o2 < NOUT) out[((size_t)b2b * NOUT + o2) * TSTEPS + (tt - 1)] = (m2n - v) - logf(s);
        }
    }

    // ---- save state for next chunk
    d_inp[(size_t)b0 * NR + r_g] = di0;
    d_inp[(size_t)b1 * NR + r_g] = di1;
    if ((r_l & 3) == 0) {
        mem1[b0 * NHID + neuron] = mm0;
        mem1[b1 * NHID + neuron] = mm1;
    }
    if (l2blk && o2 < NOUT) {
        mem2[b2b * NOUT + o2] = m2;
        spk2[b2b * NOUT + o2] = s2v;
    }
}

// ---------------- host ----------------

extern "C" void kernel_launch(void* const* d_in, const int* in_sizes, int n_in,
                              void* d_out, int out_size, void* d_ws, size_t ws_size,
                              hipStream_t stream) {
    const float* x      = (const float*)d_in[0];
    const float* W1     = (const float*)d_in[1];
    const float* b1     = (const float*)d_in[2];
    const float* tau_m1 = (const float*)d_in[3];
    const float* tau_n  = (const float*)d_in[4];
    const float* W2     = (const float*)d_in[5];
    const float* b2     = (const float*)d_in[6];
    const float* tau_m2 = (const float*)d_in[7];
    const float* mem1_0 = (const float*)d_in[8];
    const float* mem2_0 = (const float*)d_in[9];
    const int*   mask   = (const int*)d_in[10];
    float* out = (float*)d_out;

    float* ws = (float*)d_ws;
    size_t F = 0;
    float* alpha1 = ws + F; F += 1024;
    float* beta   = ws + F; F += 4096;
    float* alpha2 = ws + F; F += 32;
    float* mem1   = ws + F; F += BATCH * NHID;
    float* mem2   = ws + F; F += BATCH * NOUT;
    float* spk2   = ws + F; F += BATCH * NOUT;
    float* d_inp  = ws + F; F += BATCH * NR;
    float* W1xT   = ws + F; F += (size_t)NIN * NR;
    float* W1hTb  = ws + F; F += (size_t)256 * 16384;
    float* W2T    = ws + F; F += NHID * 32;
    uint32_t* spkg = (uint32_t*)(ws + F); F += 8192;   // double-buffered spike words
    uint32_t* bar  = (uint32_t*)(ws + F); F += 1024;   // barrier tree (root + 16 lines)
    float* ffx = ws + F;

    size_t ws_f = ws_size / 4;
    size_t avail = (ws_f > F) ? (ws_f - F) : 0;
    size_t per_t = (size_t)BATCH * NR;          // 524288 floats per timestep
    int Tc = (int)(avail / per_t);
    if (Tc < 1) Tc = 1;
    if (Tc > TSTEPS) Tc = TSTEPS;

    hipLaunchKernelGGL(setup_small, dim3(128), dim3(256), 0, stream,
                       tau_m1, tau_n, tau_m2, W2, alpha1, beta, alpha2, W2T);
    hipLaunchKernelGGL(setup_weights, dim3(2048), dim3(256), 0, stream, W1, mask, W1xT, W1hTb);
    hipLaunchKernelGGL(init_state, dim3(2048), dim3(256), 0, stream,
                       mem1_0, mem2_0, mem1, mem2, spk2, d_inp, spkg, bar);

    int chunk_start = 0;
    int barriers_done = 0;
    while (chunk_start < TSTEPS) {
        int tc = TSTEPS - chunk_start;
        if (tc > Tc) tc = Tc;
        int last = (chunk_start + tc >= TSTEPS) ? 1 : 0;

        hipLaunchKernelGGL(ffx_gemm, dim3(tc, 32), dim3(256), 0, stream,
                           x, W1xT, b1, ffx, chunk_start);
        hipLaunchKernelGGL(persist4, dim3(256), dim3(1024), 0, stream,
                           alpha1, beta, alpha2, mem1, mem2, spk2, d_inp, W1hTb, W2T,
                           ffx, b2, out, spkg, bar, chunk_start, tc, last, barriers_done);

        int iters = tc + (last ? 1 : 0);
        barriers_done += iters - 1;
        chunk_start += tc;
    }
}